// Round 7
// baseline (259.308 us; speedup 1.0000x reference)
//
#include <hip/hip_runtime.h>

// Weighted keypoint MSE loss:
//   oob = (tx<0)|(tx>1024)|(ty<0)|(ty>1024)
//   loss = sum( (oob ? 0.01 : 1.0) * ((ox-tx)^2 + (oy-ty)^2) ) / B
// Inputs: output [B,K,2] fp32, target [B,K,2] fp32, B=4096, K=4096. 268 MB read.
//
// FINAL (revert to R8, session best: bench 253.0, dispatch ~70-73 us,
// 268 MB at ~3.8 TB/s pure read). Session evidence trail:
// R1-R3: source-level ILP -> compiler re-serializes (VGPR 12/28/32). 99.7 us.
// R4: nt target + normal output (L3-pin theory): 80 us, 3.35 TB/s.
// R5: cur/next software pipeline -> collapsed by compiler again. 82 us.
// R6: inline-asm 32-deep convoy, drain vmcnt(0): 104 us REGRESSION.
//     -> MLP depth is NOT the limiter (rate cap, not latency cap).
// R7: 13/16-normal L3-retention split: FETCH unchanged (exactly half input,
//     policy-invariant), 108 us. Mixed policy on one stream hurts.
// R8: all-nt BOTH streams: ~70-73 us. Best. Monotone cache-policy ladder
//     2.69 -> 3.35 -> 3.8 TB/s = removing LLC allocate/evict work.
// R9: rolling-window counted vmcnt(4) (AITER shape, never drain to 0):
//     null (+4 us). Issue shape falsified as limiter.
// Roofline: 268.4 MB mandatory read / ~3.8 TB/s measured nt-read service
// rate ~= 71 us = where the dispatch sits. On the same runs, rocclr's own
// copyBuffer does 3.36 TB/s combined (we beat it); only write-only paths
// (fill 6.9 TB/s) go faster -- writes are posted, reads round-trip.
// CU side idle (VALUBusy ~8%), zero bank conflicts, absmax 0.0.

#define WIDTH_F  1024.0f
#define HEIGHT_F 1024.0f
#define OOB_W    0.01f
#define UNROLL   8

typedef float f32x4 __attribute__((ext_vector_type(4)));

__device__ __forceinline__ float kp_pair(f32x4 o, f32x4 t) {
    float dx = o[0] - t[0];
    float dy = o[1] - t[1];
    float sqA = dx * dx + dy * dy;
    bool oobA = (t[0] < 0.0f) || (t[0] > WIDTH_F) || (t[1] < 0.0f) || (t[1] > HEIGHT_F);
    float dz = o[2] - t[2];
    float dw = o[3] - t[3];
    float sqB = dz * dz + dw * dw;
    bool oobB = (t[2] < 0.0f) || (t[2] > WIDTH_F) || (t[3] < 0.0f) || (t[3] > HEIGHT_F);
    return (oobA ? OOB_W : 1.0f) * sqA + (oobB ? OOB_W : 1.0f) * sqB;
}

__global__ __launch_bounds__(256) void res_kp_loss_kernel(
    const f32x4* __restrict__ out4,
    const f32x4* __restrict__ tgt4,
    float* __restrict__ result,
    int n4,
    float inv_b) {
    int idx    = blockIdx.x * blockDim.x + threadIdx.x;
    int stride = gridDim.x * blockDim.x;

    float acc[UNROLL];
    #pragma unroll
    for (int u = 0; u < UNROLL; ++u) acc[u] = 0.0f;

    int i = idx;
    for (; i + (UNROLL - 1) * stride < n4; i += UNROLL * stride) {
        f32x4 o[UNROLL], t[UNROLL];
        // BOTH streams nontemporal: no LLC allocation anywhere, pure HBM
        // stream. Measured best cache policy (2.69 -> 3.35 -> 3.8 TB/s).
        #pragma unroll
        for (int u = 0; u < UNROLL; ++u)
            o[u] = __builtin_nontemporal_load(&out4[i + u * stride]);
        #pragma unroll
        for (int u = 0; u < UNROLL; ++u)
            t[u] = __builtin_nontemporal_load(&tgt4[i + u * stride]);
        asm volatile("" ::: "memory");
        #pragma unroll
        for (int u = 0; u < UNROLL; ++u) acc[u] += kp_pair(o[u], t[u]);
    }
    // tail (empty for the bench shape: 16 float4/thread, 16 % 8 == 0)
    for (; i < n4; i += stride)
        acc[0] += kp_pair(__builtin_nontemporal_load(&out4[i]),
                          __builtin_nontemporal_load(&tgt4[i]));

    float a0 = (acc[0] + acc[1]) + (acc[2] + acc[3]);
    float a1 = (acc[4] + acc[5]) + (acc[6] + acc[7]);
    float accs = a0 + a1;

    // wave-64 shuffle reduction
    #pragma unroll
    for (int off = 32; off > 0; off >>= 1)
        accs += __shfl_down(accs, off, 64);

    __shared__ float wave_sums[4];
    int lane = threadIdx.x & 63;
    int wave = threadIdx.x >> 6;
    if (lane == 0) wave_sums[wave] = accs;
    __syncthreads();

    if (threadIdx.x == 0) {
        float s = (wave_sums[0] + wave_sums[1]) + (wave_sums[2] + wave_sums[3]);
        atomicAdd(result, s * inv_b);  // device-scope by default on CDNA
    }
}

extern "C" void kernel_launch(void* const* d_in, const int* in_sizes, int n_in,
                              void* d_out, int out_size, void* d_ws, size_t ws_size,
                              hipStream_t stream) {
    const f32x4* out4 = (const f32x4*)d_in[0];  // output [B,K,2] fp32
    const f32x4* tgt4 = (const f32x4*)d_in[1];  // target [B,K,2] fp32
    float* result = (float*)d_out;

    const int total_floats = in_sizes[0];          // B*K*2 = 33,554,432
    const int n4 = total_floats / 4;               // 8,388,608 float4 per array
    const float inv_b = 1.0f / 4096.0f;            // B = 4096

    // d_out is poisoned 0xAA before every timed launch — zero it (async, capture-safe)
    hipMemsetAsync(d_out, 0, out_size * sizeof(float), stream);

    const int block = 256;
    const int grid = 2048;  // 16 float4 per thread per array
    res_kp_loss_kernel<<<grid, block, 0, stream>>>(out4, tgt4, result, n4, inv_b);
}